// Round 1
// baseline (20202.292 us; speedup 1.0000x reference)
//
#include <hip/hip_runtime.h>
#include <math.h>

// ---------------------------------------------------------------------------
// RSSM (SingleHiddenTransitionModel): 32 sequential steps, B=512.
// Round 1: correctness-first fp32 tiled-GEMM implementation.
//   per step: k_embed_state -> k_gru -> {k_embed_post, k_embed_prior} -> k_head
// Carry (belief, post_state, prior_state) is read from previous step's d_out
// slices; only hidden/hp/hq live in d_ws (6 MB).
// ---------------------------------------------------------------------------

#define B 512
#define BELIEF 1024
#define STATE 256

__device__ __forceinline__ float sigmoidf_(float x) { return 1.f / (1.f + expf(-x)); }
__device__ __forceinline__ float softplusf_(float x) {
    return fmaxf(x, 0.f) + log1pf(expf(-fabsf(x)));
}

// ---------------------------------------------------------------------------
// k_embed_state: hidden = relu([post_s | prior_s] @ w_es + b_es)
//   M=512, K=512 (256 post + 256 prior), N=1024
// ---------------------------------------------------------------------------
__global__ __launch_bounds__(256) void k_embed_state(
    const float* __restrict__ aPost, const float* __restrict__ aPrior,
    const float* __restrict__ W, const float* __restrict__ bias,
    float* __restrict__ out)
{
    __shared__ float As[64][17];
    __shared__ float Wt[16][64];
    const int tx = threadIdx.x, ty = threadIdx.y;
    const int tid = ty * 16 + tx;
    const int m0 = blockIdx.y * 64, n0 = blockIdx.x * 64;
    float acc[4][4] = {};

    for (int k0 = 0; k0 < 512; k0 += 16) {
        const int kk = tid & 15;
        const int kidx = k0 + kk;
        const float* ap = (kidx < 256) ? (aPost + kidx) : (aPrior + (kidx - 256));
#pragma unroll
        for (int p = 0; p < 4; ++p) {
            int mm = (tid >> 4) + 16 * p;
            As[mm][kk] = ap[(size_t)(m0 + mm) * 256];
        }
        const int nn = tid & 63;
#pragma unroll
        for (int p = 0; p < 4; ++p) {
            int kw = (tid >> 6) + 4 * p;
            Wt[kw][nn] = W[(size_t)(k0 + kw) * 1024 + n0 + nn];
        }
        __syncthreads();
#pragma unroll
        for (int k = 0; k < 16; ++k) {
            float a[4], b[4];
#pragma unroll
            for (int i = 0; i < 4; ++i) a[i] = As[ty + 16 * i][k];
#pragma unroll
            for (int j = 0; j < 4; ++j) b[j] = Wt[k][tx + 16 * j];
#pragma unroll
            for (int i = 0; i < 4; ++i)
#pragma unroll
                for (int j = 0; j < 4; ++j) acc[i][j] += a[i] * b[j];
        }
        __syncthreads();
    }
#pragma unroll
    for (int i = 0; i < 4; ++i) {
        int m = m0 + ty + 16 * i;
#pragma unroll
        for (int j = 0; j < 4; ++j) {
            int n = n0 + tx + 16 * j;
            out[(size_t)m * 1024 + n] = fmaxf(acc[i][j] + bias[n], 0.f);
        }
    }
}

// ---------------------------------------------------------------------------
// k_gru: belief_new = GRU(hidden, belief_prev)
//   gates: r = sig(ir+hr), z = sig(iz+hz), n = tanh(inn + r*hn)
//   r/z accumulate over K=2048 ([hidden|belief] x [w_ih;w_hh]);
//   inn (hidden x w_ih) and hn (belief x w_hh) kept separate.
// ---------------------------------------------------------------------------
__global__ __launch_bounds__(256) void k_gru(
    const float* __restrict__ hidden, const float* __restrict__ beliefPrev,
    const float* __restrict__ w_ih, const float* __restrict__ w_hh,
    const float* __restrict__ b_ih, const float* __restrict__ b_hh,
    float* __restrict__ beliefOut)
{
    __shared__ float As[64][17];
    __shared__ float Wr[16][64], Wz[16][64], Wn[16][64];
    const int tx = threadIdx.x, ty = threadIdx.y;
    const int tid = ty * 16 + tx;
    const int m0 = blockIdx.y * 64, n0 = blockIdx.x * 64;
    float racc[4][4] = {}, zacc[4][4] = {}, nia[4][4] = {}, nha[4][4] = {};

#pragma unroll
    for (int phase = 0; phase < 2; ++phase) {
        const float* A = (phase == 0) ? hidden : beliefPrev;
        const float* W = (phase == 0) ? w_ih : w_hh;
        for (int k0 = 0; k0 < 1024; k0 += 16) {
            const int kk = tid & 15;
#pragma unroll
            for (int p = 0; p < 4; ++p) {
                int mm = (tid >> 4) + 16 * p;
                As[mm][kk] = A[(size_t)(m0 + mm) * 1024 + k0 + kk];
            }
            const int nn = tid & 63;
#pragma unroll
            for (int p = 0; p < 4; ++p) {
                int kw = (tid >> 6) + 4 * p;
                const float* wrow = W + (size_t)(k0 + kw) * 3072;
                Wr[kw][nn] = wrow[n0 + nn];
                Wz[kw][nn] = wrow[1024 + n0 + nn];
                Wn[kw][nn] = wrow[2048 + n0 + nn];
            }
            __syncthreads();
#pragma unroll
            for (int k = 0; k < 16; ++k) {
                float a[4];
#pragma unroll
                for (int i = 0; i < 4; ++i) a[i] = As[ty + 16 * i][k];
#pragma unroll
                for (int j = 0; j < 4; ++j) {
                    float wr = Wr[k][tx + 16 * j];
                    float wz = Wz[k][tx + 16 * j];
                    float wn = Wn[k][tx + 16 * j];
#pragma unroll
                    for (int i = 0; i < 4; ++i) {
                        racc[i][j] += a[i] * wr;
                        zacc[i][j] += a[i] * wz;
                        if (phase == 0) nia[i][j] += a[i] * wn;
                        else            nha[i][j] += a[i] * wn;
                    }
                }
            }
            __syncthreads();
        }
    }
#pragma unroll
    for (int i = 0; i < 4; ++i) {
        int m = m0 + ty + 16 * i;
#pragma unroll
        for (int j = 0; j < 4; ++j) {
            int n = n0 + tx + 16 * j;
            float r = sigmoidf_(racc[i][j] + b_ih[n] + b_hh[n]);
            float z = sigmoidf_(zacc[i][j] + b_ih[n + 1024] + b_hh[n + 1024]);
            float ng = tanhf(nia[i][j] + b_ih[n + 2048] + r * (nha[i][j] + b_hh[n + 2048]));
            float h = beliefPrev[(size_t)m * 1024 + n];
            beliefOut[(size_t)m * 1024 + n] = (1.f - z) * ng + z * h;
        }
    }
}

// ---------------------------------------------------------------------------
// k_embed_post: hp = relu([belief | obs_t] @ w_ebpo + b_ebpo)
//   M=512, K=2048, N=1024
// ---------------------------------------------------------------------------
__global__ __launch_bounds__(256) void k_embed_post(
    const float* __restrict__ belief, const float* __restrict__ obs,
    const float* __restrict__ W, const float* __restrict__ bias,
    float* __restrict__ out)
{
    __shared__ float As[64][17];
    __shared__ float Wt[16][64];
    const int tx = threadIdx.x, ty = threadIdx.y;
    const int tid = ty * 16 + tx;
    const int m0 = blockIdx.y * 64, n0 = blockIdx.x * 64;
    float acc[4][4] = {};

    for (int k0 = 0; k0 < 2048; k0 += 16) {
        const float* A = (k0 < 1024) ? belief : obs;
        const int krel = (k0 < 1024) ? k0 : (k0 - 1024);
        const int kk = tid & 15;
#pragma unroll
        for (int p = 0; p < 4; ++p) {
            int mm = (tid >> 4) + 16 * p;
            As[mm][kk] = A[(size_t)(m0 + mm) * 1024 + krel + kk];
        }
        const int nn = tid & 63;
#pragma unroll
        for (int p = 0; p < 4; ++p) {
            int kw = (tid >> 6) + 4 * p;
            Wt[kw][nn] = W[(size_t)(k0 + kw) * 1024 + n0 + nn];
        }
        __syncthreads();
#pragma unroll
        for (int k = 0; k < 16; ++k) {
            float a[4], b[4];
#pragma unroll
            for (int i = 0; i < 4; ++i) a[i] = As[ty + 16 * i][k];
#pragma unroll
            for (int j = 0; j < 4; ++j) b[j] = Wt[k][tx + 16 * j];
#pragma unroll
            for (int i = 0; i < 4; ++i)
#pragma unroll
                for (int j = 0; j < 4; ++j) acc[i][j] += a[i] * b[j];
        }
        __syncthreads();
    }
#pragma unroll
    for (int i = 0; i < 4; ++i) {
        int m = m0 + ty + 16 * i;
#pragma unroll
        for (int j = 0; j < 4; ++j) {
            int n = n0 + tx + 16 * j;
            out[(size_t)m * 1024 + n] = fmaxf(acc[i][j] + bias[n], 0.f);
        }
    }
}

// ---------------------------------------------------------------------------
// k_embed_prior: hq = relu([belief | pose] @ w_ebpr + b_ebpr)
//   M=512, K=1024 (+ rank-6 pose update in epilogue), N=1024
// ---------------------------------------------------------------------------
__global__ __launch_bounds__(256) void k_embed_prior(
    const float* __restrict__ belief, const float* __restrict__ pose,
    const float* __restrict__ W, const float* __restrict__ bias,
    float* __restrict__ out)
{
    __shared__ float As[64][17];
    __shared__ float Wt[16][64];
    const int tx = threadIdx.x, ty = threadIdx.y;
    const int tid = ty * 16 + tx;
    const int m0 = blockIdx.y * 64, n0 = blockIdx.x * 64;
    float acc[4][4] = {};

    for (int k0 = 0; k0 < 1024; k0 += 16) {
        const int kk = tid & 15;
#pragma unroll
        for (int p = 0; p < 4; ++p) {
            int mm = (tid >> 4) + 16 * p;
            As[mm][kk] = belief[(size_t)(m0 + mm) * 1024 + k0 + kk];
        }
        const int nn = tid & 63;
#pragma unroll
        for (int p = 0; p < 4; ++p) {
            int kw = (tid >> 6) + 4 * p;
            Wt[kw][nn] = W[(size_t)(k0 + kw) * 1024 + n0 + nn];
        }
        __syncthreads();
#pragma unroll
        for (int k = 0; k < 16; ++k) {
            float a[4], b[4];
#pragma unroll
            for (int i = 0; i < 4; ++i) a[i] = As[ty + 16 * i][k];
#pragma unroll
            for (int j = 0; j < 4; ++j) b[j] = Wt[k][tx + 16 * j];
#pragma unroll
            for (int i = 0; i < 4; ++i)
#pragma unroll
                for (int j = 0; j < 4; ++j) acc[i][j] += a[i] * b[j];
        }
        __syncthreads();
    }
#pragma unroll
    for (int i = 0; i < 4; ++i) {
        int m = m0 + ty + 16 * i;
#pragma unroll
        for (int j = 0; j < 4; ++j) {
            int n = n0 + tx + 16 * j;
            float v = acc[i][j] + bias[n];
#pragma unroll
            for (int p = 0; p < 6; ++p)
                v += pose[(size_t)m * 6 + p] * W[(size_t)(1024 + p) * 1024 + n];
            out[(size_t)m * 1024 + n] = fmaxf(v, 0.f);
        }
    }
}

// ---------------------------------------------------------------------------
// k_head: mean/std/state for posterior (z=0, from hp) and prior (z=1, from hq).
//   W is [1024, 512]; col c<256 -> mean, col c+256 -> std_raw.
//   Each thread computes paired mean+std cols so state fuses in-epilogue.
// ---------------------------------------------------------------------------
__global__ __launch_bounds__(256) void k_head(
    const float* __restrict__ hp, const float* __restrict__ hq,
    const float* __restrict__ w_spo, const float* __restrict__ b_spo,
    const float* __restrict__ w_spr, const float* __restrict__ b_spr,
    const float* __restrict__ noisePost, const float* __restrict__ noisePrior,
    float* __restrict__ postMean, float* __restrict__ postStd, float* __restrict__ postState,
    float* __restrict__ priMean, float* __restrict__ priStd, float* __restrict__ priState)
{
    const bool prior = (blockIdx.z == 1);
    const float* A = prior ? hq : hp;
    const float* W = prior ? w_spr : w_spo;
    const float* bias = prior ? b_spr : b_spo;
    const float* noise = prior ? noisePrior : noisePost;
    float* mOut = prior ? priMean : postMean;
    float* sOut = prior ? priStd : postStd;
    float* stOut = prior ? priState : postState;

    __shared__ float As[64][17];
    __shared__ float Wm[16][64], Wsd[16][64];
    const int tx = threadIdx.x, ty = threadIdx.y;
    const int tid = ty * 16 + tx;
    const int m0 = blockIdx.y * 64, c0 = blockIdx.x * 64;
    float macc[4][4] = {}, sacc[4][4] = {};

    for (int k0 = 0; k0 < 1024; k0 += 16) {
        const int kk = tid & 15;
#pragma unroll
        for (int p = 0; p < 4; ++p) {
            int mm = (tid >> 4) + 16 * p;
            As[mm][kk] = A[(size_t)(m0 + mm) * 1024 + k0 + kk];
        }
        const int nn = tid & 63;
#pragma unroll
        for (int p = 0; p < 4; ++p) {
            int kw = (tid >> 6) + 4 * p;
            const float* wrow = W + (size_t)(k0 + kw) * 512;
            Wm[kw][nn] = wrow[c0 + nn];
            Wsd[kw][nn] = wrow[256 + c0 + nn];
        }
        __syncthreads();
#pragma unroll
        for (int k = 0; k < 16; ++k) {
            float a[4];
#pragma unroll
            for (int i = 0; i < 4; ++i) a[i] = As[ty + 16 * i][k];
#pragma unroll
            for (int j = 0; j < 4; ++j) {
                float wm = Wm[k][tx + 16 * j];
                float wsd = Wsd[k][tx + 16 * j];
#pragma unroll
                for (int i = 0; i < 4; ++i) {
                    macc[i][j] += a[i] * wm;
                    sacc[i][j] += a[i] * wsd;
                }
            }
        }
        __syncthreads();
    }
#pragma unroll
    for (int i = 0; i < 4; ++i) {
        int m = m0 + ty + 16 * i;
#pragma unroll
        for (int j = 0; j < 4; ++j) {
            int c = c0 + tx + 16 * j;
            float mean = macc[i][j] + bias[c];
            float sd = softplusf_(sacc[i][j] + bias[c + 256]) + 0.1f;
            float st = mean + sd * noise[(size_t)m * 256 + c];
            mOut[(size_t)m * 256 + c] = mean;
            sOut[(size_t)m * 256 + c] = sd;
            stOut[(size_t)m * 256 + c] = st;
        }
    }
}

// ---------------------------------------------------------------------------
extern "C" void kernel_launch(void* const* d_in, const int* in_sizes, int n_in,
                              void* d_out, int out_size, void* d_ws, size_t ws_size,
                              hipStream_t stream)
{
    const float* prev_state  = (const float*)d_in[0];
    const float* prev_belief = (const float*)d_in[1];
    const float* poses       = (const float*)d_in[2];   // [32,512,6]
    const float* obs         = (const float*)d_in[3];   // [32,512,1024]
    const float* post_noise  = (const float*)d_in[4];   // [32,512,256]
    const float* prior_noise = (const float*)d_in[5];
    const float* w_es   = (const float*)d_in[6];
    const float* b_es   = (const float*)d_in[7];
    const float* w_ih   = (const float*)d_in[8];
    const float* w_hh   = (const float*)d_in[9];
    const float* b_ih   = (const float*)d_in[10];
    const float* b_hh   = (const float*)d_in[11];
    const float* w_ebpo = (const float*)d_in[12];
    const float* b_ebpo = (const float*)d_in[13];
    const float* w_spo  = (const float*)d_in[14];
    const float* b_spo  = (const float*)d_in[15];
    const float* w_ebpr = (const float*)d_in[16];
    const float* b_ebpr = (const float*)d_in[17];
    const float* w_spr  = (const float*)d_in[18];
    const float* b_spr  = (const float*)d_in[19];

    float* out = (float*)d_out;
    float* beliefs    = out;                  // [32][512][1024]
    float* priStates  = out + 16777216;       // [32][512][256]
    float* priMeans   = out + 20971520;
    float* priStds    = out + 25165824;
    float* postStates = out + 29360128;
    float* postMeans  = out + 33554432;
    float* postStds   = out + 37748736;

    float* ws = (float*)d_ws;
    float* hidden = ws;                // 512*1024
    float* hp     = ws + 524288;       // 512*1024
    float* hq     = ws + 1048576;      // 512*1024

    dim3 blk(16, 16);
    for (int t = 0; t < 32; ++t) {
        const float* aPost   = t ? (postStates + (size_t)(t - 1) * 131072) : prev_state;
        const float* aPrior  = t ? (priStates  + (size_t)(t - 1) * 131072) : prev_state;
        const float* belPrev = t ? (beliefs + (size_t)(t - 1) * 524288) : prev_belief;
        float* belT = beliefs + (size_t)t * 524288;

        hipLaunchKernelGGL(k_embed_state, dim3(16, 8), blk, 0, stream,
                           aPost, aPrior, w_es, b_es, hidden);
        hipLaunchKernelGGL(k_gru, dim3(16, 8), blk, 0, stream,
                           hidden, belPrev, w_ih, w_hh, b_ih, b_hh, belT);
        hipLaunchKernelGGL(k_embed_post, dim3(16, 8), blk, 0, stream,
                           belT, obs + (size_t)t * 524288, w_ebpo, b_ebpo, hp);
        hipLaunchKernelGGL(k_embed_prior, dim3(16, 8), blk, 0, stream,
                           belT, poses + (size_t)t * 3072, w_ebpr, b_ebpr, hq);
        hipLaunchKernelGGL(k_head, dim3(4, 8, 2), blk, 0, stream,
                           hp, hq, w_spo, b_spo, w_spr, b_spr,
                           post_noise + (size_t)t * 131072, prior_noise + (size_t)t * 131072,
                           postMeans + (size_t)t * 131072, postStds + (size_t)t * 131072,
                           postStates + (size_t)t * 131072,
                           priMeans + (size_t)t * 131072, priStds + (size_t)t * 131072,
                           priStates + (size_t)t * 131072);
    }
}

// Round 2
// 3770.136 us; speedup vs baseline: 5.3585x; 5.3585x over previous
//
#include <hip/hip_runtime.h>
#include <math.h>

// ---------------------------------------------------------------------------
// RSSM, Round 2: bf16 MFMA (16x16x32) rewrite.
//  - Pre-pass: swizzle all weights fp32 -> bf16 into MFMA B-fragment order.
//  - Wave tile 32x32 (2x2 acc frags), 2-wave (128-thread) blocks, no LDS:
//    A-frags read row-major bf16 from ws; B-frags read pre-swizzled (coalesced).
//  - GRU: r/z accumulate over K=2048 (hidden|belief), inn/hn separate; one kernel.
//  - Heads: paired mean/std columns; state = mean + sd*noise fused in epilogue.
// ---------------------------------------------------------------------------

typedef __attribute__((ext_vector_type(8))) short bf16x8;
typedef __attribute__((ext_vector_type(4))) float f32x4;

#define MFMA(a, b, c) __builtin_amdgcn_mfma_f32_16x16x32_bf16(a, b, c, 0, 0, 0)

__device__ __forceinline__ short f2bf(float f) {
    unsigned u = __float_as_uint(f);
    u += 0x7FFF + ((u >> 16) & 1);   // round-to-nearest-even
    return (short)(u >> 16);
}
__device__ __forceinline__ float sigmoidf_(float x) { return 1.f / (1.f + expf(-x)); }
__device__ __forceinline__ float softplusf_(float x) {
    return fmaxf(x, 0.f) + log1pf(expf(-fabsf(x)));
}
__device__ __forceinline__ f32x4 zero4() { f32x4 v = {0.f, 0.f, 0.f, 0.f}; return v; }

// B-frag pre-swizzle: out[((nt*KT + kt)*64 + lane)*8 + j] =
//   bf16( W[(kt*32 + (lane>>4)*8 + j)*N + nt*16 + (lane&15)] )
// One wave per (nt, kt) tile; gw enumerates nt*KT + kt.
__global__ __launch_bounds__(256) void k_swizzle(const float* __restrict__ W,
                                                 short* __restrict__ out,
                                                 int KT, int N)
{
    int gw = blockIdx.x * 4 + (threadIdx.x >> 6);
    int lane = threadIdx.x & 63;
    int nt = gw / KT, kt = gw % KT;
    const float* src = W + (size_t)(kt * 32 + (lane >> 4) * 8) * N + nt * 16 + (lane & 15);
    short tmp[8];
#pragma unroll
    for (int j = 0; j < 8; ++j) tmp[j] = f2bf(src[(size_t)j * N]);
    *(bf16x8*)(out + (((size_t)gw * 64 + lane) << 3)) = *(const bf16x8*)tmp;
}

// Init: stateCat[512][512] (post|prior both = prev_state) and belief buf1 bf16.
__global__ __launch_bounds__(256) void k_init(const float* __restrict__ prev_state,
                                              const float* __restrict__ prev_belief,
                                              short* __restrict__ stateCat,
                                              short* __restrict__ belief1)
{
    int i = blockIdx.x * 256 + threadIdx.x;
    if (i < 262144) {
        int m = i >> 9, c = i & 511;
        stateCat[i] = f2bf(prev_state[m * 256 + (c & 255)]);
    } else {
        int j = i - 262144;
        belief1[j] = f2bf(prev_belief[j]);
    }
}

__device__ __forceinline__ bf16x8 loadA16(const short* A, int m0, int kbyte16, int strideElems, int lane) {
    return *(const bf16x8*)(A + (size_t)(m0 + (lane & 15)) * strideElems + kbyte16 + ((lane >> 4) << 3));
}
__device__ __forceinline__ bf16x8 loadB16(const short* Bsw, size_t tileIdx, int lane) {
    return *(const bf16x8*)(Bsw + ((tileIdx * 64 + lane) << 3));
}

// ---------------------------------------------------------------------------
// embed_state: hidden = relu(stateCat @ w_es + b_es).  M=512,K=512,N=1024.
// 512 waves: mt(16) x ntile(32 of 32 cols).
// ---------------------------------------------------------------------------
__global__ __launch_bounds__(128) void k_embed_state(
    const short* __restrict__ A, const short* __restrict__ Bsw,
    const float* __restrict__ bias, short* __restrict__ outBf)
{
    int gw = blockIdx.x * 2 + (threadIdx.x >> 6);
    int lane = threadIdx.x & 63;
    int mt = gw >> 5, ntile = gw & 31;
    int m0 = mt * 32, n0 = ntile * 32;
    const int KT = 16;
    f32x4 acc[2][2];
    acc[0][0] = zero4(); acc[0][1] = zero4(); acc[1][0] = zero4(); acc[1][1] = zero4();
    for (int kt = 0; kt < KT; ++kt) {
        bf16x8 a0 = loadA16(A, m0, kt * 32, 512, lane);
        bf16x8 a1 = loadA16(A, m0 + 16, kt * 32, 512, lane);
        bf16x8 b0 = loadB16(Bsw, (size_t)(ntile * 2) * KT + kt, lane);
        bf16x8 b1 = loadB16(Bsw, (size_t)(ntile * 2 + 1) * KT + kt, lane);
        acc[0][0] = MFMA(a0, b0, acc[0][0]);
        acc[0][1] = MFMA(a0, b1, acc[0][1]);
        acc[1][0] = MFMA(a1, b0, acc[1][0]);
        acc[1][1] = MFMA(a1, b1, acc[1][1]);
    }
    int q = lane >> 4, cl = lane & 15;
#pragma unroll
    for (int im = 0; im < 2; ++im)
#pragma unroll
    for (int jn = 0; jn < 2; ++jn)
#pragma unroll
    for (int i = 0; i < 4; ++i) {
        int m = m0 + im * 16 + q * 4 + i;
        int n = n0 + jn * 16 + cl;
        outBf[(size_t)m * 1024 + n] = f2bf(fmaxf(acc[im][jn][i] + bias[n], 0.f));
    }
}

// ---------------------------------------------------------------------------
// GRU: 512 waves: mt(16) x ntile(32).  3 gates fused; K=2048 for r/z.
// ---------------------------------------------------------------------------
__global__ __launch_bounds__(128) void k_gru(
    const short* __restrict__ Hbf, const short* __restrict__ Pbf,
    const float* __restrict__ Pf32,
    const short* __restrict__ sw_ih, const short* __restrict__ sw_hh,
    const float* __restrict__ b_ih, const float* __restrict__ b_hh,
    float* __restrict__ belF32, short* __restrict__ belBf)
{
    int gw = blockIdx.x * 2 + (threadIdx.x >> 6);
    int lane = threadIdx.x & 63;
    int mt = gw >> 5, ntile = gw & 31;
    int m0 = mt * 32, n0 = ntile * 32;
    f32x4 r[2][2], z[2][2], ni[2][2], nh[2][2];
#pragma unroll
    for (int a = 0; a < 2; ++a)
#pragma unroll
    for (int b = 0; b < 2; ++b) { r[a][b] = zero4(); z[a][b] = zero4(); ni[a][b] = zero4(); nh[a][b] = zero4(); }

#define GATE4(ACC, SW, NTBASE) { \
        bf16x8 b0 = loadB16(SW, (size_t)(NTBASE) * 32 + kt, lane); \
        bf16x8 b1 = loadB16(SW, (size_t)((NTBASE) + 1) * 32 + kt, lane); \
        ACC[0][0] = MFMA(a0, b0, ACC[0][0]); ACC[0][1] = MFMA(a0, b1, ACC[0][1]); \
        ACC[1][0] = MFMA(a1, b0, ACC[1][0]); ACC[1][1] = MFMA(a1, b1, ACC[1][1]); }

    // phase 0: hidden @ w_ih  (r, z, inn)
    for (int kt = 0; kt < 32; ++kt) {
        bf16x8 a0 = loadA16(Hbf, m0, kt * 32, 1024, lane);
        bf16x8 a1 = loadA16(Hbf, m0 + 16, kt * 32, 1024, lane);
        GATE4(r,  sw_ih, 0 * 64 + ntile * 2);
        GATE4(z,  sw_ih, 1 * 64 + ntile * 2);
        GATE4(ni, sw_ih, 2 * 64 + ntile * 2);
    }
    // phase 1: beliefPrev @ w_hh  (r, z, hn)
    for (int kt = 0; kt < 32; ++kt) {
        bf16x8 a0 = loadA16(Pbf, m0, kt * 32, 1024, lane);
        bf16x8 a1 = loadA16(Pbf, m0 + 16, kt * 32, 1024, lane);
        GATE4(r,  sw_hh, 0 * 64 + ntile * 2);
        GATE4(z,  sw_hh, 1 * 64 + ntile * 2);
        GATE4(nh, sw_hh, 2 * 64 + ntile * 2);
    }
#undef GATE4

    int q = lane >> 4, cl = lane & 15;
#pragma unroll
    for (int im = 0; im < 2; ++im)
#pragma unroll
    for (int jn = 0; jn < 2; ++jn)
#pragma unroll
    for (int i = 0; i < 4; ++i) {
        int m = m0 + im * 16 + q * 4 + i;
        int n = n0 + jn * 16 + cl;
        float rr = sigmoidf_(r[im][jn][i] + b_ih[n] + b_hh[n]);
        float zz = sigmoidf_(z[im][jn][i] + b_ih[1024 + n] + b_hh[1024 + n]);
        float ng = tanhf(ni[im][jn][i] + b_ih[2048 + n] + rr * (nh[im][jn][i] + b_hh[2048 + n]));
        float h = Pf32[(size_t)m * 1024 + n];
        float v = (1.f - zz) * ng + zz * h;
        belF32[(size_t)m * 1024 + n] = v;
        belBf[(size_t)m * 1024 + n] = f2bf(v);
    }
}

// ---------------------------------------------------------------------------
// embed_post: hp = relu([belief | obs] @ w_ebpo + b).  K=2048 (obs half fp32).
// ---------------------------------------------------------------------------
__global__ __launch_bounds__(128) void k_embed_post(
    const short* __restrict__ Bel, const float* __restrict__ Obs,
    const short* __restrict__ Bsw, const float* __restrict__ bias,
    short* __restrict__ outBf)
{
    int gw = blockIdx.x * 2 + (threadIdx.x >> 6);
    int lane = threadIdx.x & 63;
    int mt = gw >> 5, ntile = gw & 31;
    int m0 = mt * 32, n0 = ntile * 32;
    const int KT = 64;
    f32x4 acc[2][2];
    acc[0][0] = zero4(); acc[0][1] = zero4(); acc[1][0] = zero4(); acc[1][1] = zero4();
    for (int kt = 0; kt < 32; ++kt) {
        bf16x8 a0 = loadA16(Bel, m0, kt * 32, 1024, lane);
        bf16x8 a1 = loadA16(Bel, m0 + 16, kt * 32, 1024, lane);
        bf16x8 b0 = loadB16(Bsw, (size_t)(ntile * 2) * KT + kt, lane);
        bf16x8 b1 = loadB16(Bsw, (size_t)(ntile * 2 + 1) * KT + kt, lane);
        acc[0][0] = MFMA(a0, b0, acc[0][0]);
        acc[0][1] = MFMA(a0, b1, acc[0][1]);
        acc[1][0] = MFMA(a1, b0, acc[1][0]);
        acc[1][1] = MFMA(a1, b1, acc[1][1]);
    }
    for (int kt = 32; kt < 64; ++kt) {
        int ko = (kt - 32) * 32 + ((lane >> 4) << 3);
        const float* p0 = Obs + (size_t)(m0 + (lane & 15)) * 1024 + ko;
        const float* p1 = Obs + (size_t)(m0 + 16 + (lane & 15)) * 1024 + ko;
        short t0[8], t1[8];
#pragma unroll
        for (int j = 0; j < 8; ++j) { t0[j] = f2bf(p0[j]); t1[j] = f2bf(p1[j]); }
        bf16x8 a0 = *(const bf16x8*)t0;
        bf16x8 a1 = *(const bf16x8*)t1;
        bf16x8 b0 = loadB16(Bsw, (size_t)(ntile * 2) * KT + kt, lane);
        bf16x8 b1 = loadB16(Bsw, (size_t)(ntile * 2 + 1) * KT + kt, lane);
        acc[0][0] = MFMA(a0, b0, acc[0][0]);
        acc[0][1] = MFMA(a0, b1, acc[0][1]);
        acc[1][0] = MFMA(a1, b0, acc[1][0]);
        acc[1][1] = MFMA(a1, b1, acc[1][1]);
    }
    int q = lane >> 4, cl = lane & 15;
#pragma unroll
    for (int im = 0; im < 2; ++im)
#pragma unroll
    for (int jn = 0; jn < 2; ++jn)
#pragma unroll
    for (int i = 0; i < 4; ++i) {
        int m = m0 + im * 16 + q * 4 + i;
        int n = n0 + jn * 16 + cl;
        outBf[(size_t)m * 1024 + n] = f2bf(fmaxf(acc[im][jn][i] + bias[n], 0.f));
    }
}

// ---------------------------------------------------------------------------
// embed_prior: hq = relu([belief | pose] @ w_ebpr + b). K=1024 + rank-6 fp32 epi.
// ---------------------------------------------------------------------------
__global__ __launch_bounds__(128) void k_embed_prior(
    const short* __restrict__ Bel, const float* __restrict__ Pose,
    const short* __restrict__ Bsw, const float* __restrict__ Wf,
    const float* __restrict__ bias, short* __restrict__ outBf)
{
    int gw = blockIdx.x * 2 + (threadIdx.x >> 6);
    int lane = threadIdx.x & 63;
    int mt = gw >> 5, ntile = gw & 31;
    int m0 = mt * 32, n0 = ntile * 32;
    const int KT = 32;
    f32x4 acc[2][2];
    acc[0][0] = zero4(); acc[0][1] = zero4(); acc[1][0] = zero4(); acc[1][1] = zero4();
    for (int kt = 0; kt < KT; ++kt) {
        bf16x8 a0 = loadA16(Bel, m0, kt * 32, 1024, lane);
        bf16x8 a1 = loadA16(Bel, m0 + 16, kt * 32, 1024, lane);
        bf16x8 b0 = loadB16(Bsw, (size_t)(ntile * 2) * KT + kt, lane);
        bf16x8 b1 = loadB16(Bsw, (size_t)(ntile * 2 + 1) * KT + kt, lane);
        acc[0][0] = MFMA(a0, b0, acc[0][0]);
        acc[0][1] = MFMA(a0, b1, acc[0][1]);
        acc[1][0] = MFMA(a1, b0, acc[1][0]);
        acc[1][1] = MFMA(a1, b1, acc[1][1]);
    }
    int q = lane >> 4, cl = lane & 15;
#pragma unroll
    for (int im = 0; im < 2; ++im)
#pragma unroll
    for (int jn = 0; jn < 2; ++jn)
#pragma unroll
    for (int i = 0; i < 4; ++i) {
        int m = m0 + im * 16 + q * 4 + i;
        int n = n0 + jn * 16 + cl;
        float v = acc[im][jn][i] + bias[n];
#pragma unroll
        for (int p = 0; p < 6; ++p)
            v += Pose[(size_t)m * 6 + p] * Wf[(size_t)(1024 + p) * 1024 + n];
        outBf[(size_t)m * 1024 + n] = f2bf(fmaxf(v, 0.f));
    }
}

// ---------------------------------------------------------------------------
// head: mean/std/state for posterior (br=0 from hp) / prior (br=1 from hq).
// 256 waves: br(2) x mt(16) x ct(8 of 32 cols).  Mean/std paired per wave.
// ---------------------------------------------------------------------------
__global__ __launch_bounds__(128) void k_head(
    const short* __restrict__ Hp, const short* __restrict__ Hq,
    const short* __restrict__ sw_spo, const short* __restrict__ sw_spr,
    const float* __restrict__ b_spo, const float* __restrict__ b_spr,
    const float* __restrict__ nPost, const float* __restrict__ nPri,
    float* __restrict__ pM, float* __restrict__ pS, float* __restrict__ pSt,
    float* __restrict__ qM, float* __restrict__ qS, float* __restrict__ qSt,
    short* __restrict__ stateCat)
{
    int gw = blockIdx.x * 2 + (threadIdx.x >> 6);
    int lane = threadIdx.x & 63;
    int br = gw >> 7, rem = gw & 127;
    int mt = rem >> 3, ct = rem & 7;
    int m0 = mt * 32, c0 = ct * 32;
    const short* A = br ? Hq : Hp;
    const short* Bsw = br ? sw_spr : sw_spo;
    const float* bias = br ? b_spr : b_spo;
    const float* noise = br ? nPri : nPost;
    float* mO = br ? qM : pM;
    float* sO = br ? qS : pS;
    float* stO = br ? qSt : pSt;
    int catOff = br ? 256 : 0;
    const int KT = 32;
    f32x4 ma[2][2], sa[2][2];
#pragma unroll
    for (int a = 0; a < 2; ++a)
#pragma unroll
    for (int b = 0; b < 2; ++b) { ma[a][b] = zero4(); sa[a][b] = zero4(); }
    for (int kt = 0; kt < KT; ++kt) {
        bf16x8 a0 = loadA16(A, m0, kt * 32, 1024, lane);
        bf16x8 a1 = loadA16(A, m0 + 16, kt * 32, 1024, lane);
        bf16x8 bm0 = loadB16(Bsw, (size_t)(ct * 2) * KT + kt, lane);
        bf16x8 bm1 = loadB16(Bsw, (size_t)(ct * 2 + 1) * KT + kt, lane);
        bf16x8 bs0 = loadB16(Bsw, (size_t)(16 + ct * 2) * KT + kt, lane);
        bf16x8 bs1 = loadB16(Bsw, (size_t)(16 + ct * 2 + 1) * KT + kt, lane);
        ma[0][0] = MFMA(a0, bm0, ma[0][0]); ma[0][1] = MFMA(a0, bm1, ma[0][1]);
        ma[1][0] = MFMA(a1, bm0, ma[1][0]); ma[1][1] = MFMA(a1, bm1, ma[1][1]);
        sa[0][0] = MFMA(a0, bs0, sa[0][0]); sa[0][1] = MFMA(a0, bs1, sa[0][1]);
        sa[1][0] = MFMA(a1, bs0, sa[1][0]); sa[1][1] = MFMA(a1, bs1, sa[1][1]);
    }
    int q = lane >> 4, cl = lane & 15;
#pragma unroll
    for (int im = 0; im < 2; ++im)
#pragma unroll
    for (int jn = 0; jn < 2; ++jn)
#pragma unroll
    for (int i = 0; i < 4; ++i) {
        int m = m0 + im * 16 + q * 4 + i;
        int c = c0 + jn * 16 + cl;
        float mean = ma[im][jn][i] + bias[c];
        float sd = softplusf_(sa[im][jn][i] + bias[c + 256]) + 0.1f;
        float st = mean + sd * noise[(size_t)m * 256 + c];
        mO[(size_t)m * 256 + c] = mean;
        sO[(size_t)m * 256 + c] = sd;
        stO[(size_t)m * 256 + c] = st;
        stateCat[(size_t)m * 512 + catOff + c] = f2bf(st);
    }
}

// ---------------------------------------------------------------------------
extern "C" void kernel_launch(void* const* d_in, const int* in_sizes, int n_in,
                              void* d_out, int out_size, void* d_ws, size_t ws_size,
                              hipStream_t stream)
{
    const float* prev_state  = (const float*)d_in[0];
    const float* prev_belief = (const float*)d_in[1];
    const float* poses       = (const float*)d_in[2];
    const float* obs         = (const float*)d_in[3];
    const float* post_noise  = (const float*)d_in[4];
    const float* prior_noise = (const float*)d_in[5];
    const float* w_es   = (const float*)d_in[6];
    const float* b_es   = (const float*)d_in[7];
    const float* w_ih   = (const float*)d_in[8];
    const float* w_hh   = (const float*)d_in[9];
    const float* b_ih   = (const float*)d_in[10];
    const float* b_hh   = (const float*)d_in[11];
    const float* w_ebpo = (const float*)d_in[12];
    const float* b_ebpo = (const float*)d_in[13];
    const float* w_spo  = (const float*)d_in[14];
    const float* b_spo  = (const float*)d_in[15];
    const float* w_ebpr = (const float*)d_in[16];
    const float* b_ebpr = (const float*)d_in[17];
    const float* w_spr  = (const float*)d_in[18];
    const float* b_spr  = (const float*)d_in[19];

    float* out = (float*)d_out;
    float* beliefs    = out;
    float* priStates  = out + 16777216;
    float* priMeans   = out + 20971520;
    float* priStds    = out + 25165824;
    float* postStates = out + 29360128;
    float* postMeans  = out + 33554432;
    float* postStds   = out + 37748736;

    short* ws = (short*)d_ws;
    size_t o = 0;
    short* sw_es   = ws + o; o += (size_t)512 * 1024;
    short* sw_ih   = ws + o; o += (size_t)1024 * 3072;
    short* sw_hh   = ws + o; o += (size_t)1024 * 3072;
    short* sw_ebpo = ws + o; o += (size_t)2048 * 1024;
    short* sw_ebpr = ws + o; o += (size_t)1024 * 1024;
    short* sw_spo  = ws + o; o += (size_t)1024 * 512;
    short* sw_spr  = ws + o; o += (size_t)1024 * 512;
    short* hidden  = ws + o; o += (size_t)512 * 1024;
    short* belBuf0 = ws + o; o += (size_t)512 * 1024;
    short* belBuf1 = ws + o; o += (size_t)512 * 1024;
    short* hpBuf   = ws + o; o += (size_t)512 * 1024;
    short* hqBuf   = ws + o; o += (size_t)512 * 1024;
    short* stateCat = ws + o; o += (size_t)512 * 512;

    // ---- pre-pass: weight swizzles (NT*KT waves each, 4 waves/block) ----
    k_swizzle<<<dim3(256),  dim3(256), 0, stream>>>(w_es,   sw_es,   16, 1024);
    k_swizzle<<<dim3(1536), dim3(256), 0, stream>>>(w_ih,   sw_ih,   32, 3072);
    k_swizzle<<<dim3(1536), dim3(256), 0, stream>>>(w_hh,   sw_hh,   32, 3072);
    k_swizzle<<<dim3(1024), dim3(256), 0, stream>>>(w_ebpo, sw_ebpo, 64, 1024);
    k_swizzle<<<dim3(512),  dim3(256), 0, stream>>>(w_ebpr, sw_ebpr, 32, 1024);
    k_swizzle<<<dim3(256),  dim3(256), 0, stream>>>(w_spo,  sw_spo,  32, 512);
    k_swizzle<<<dim3(256),  dim3(256), 0, stream>>>(w_spr,  sw_spr,  32, 512);
    k_init<<<dim3(3072), dim3(256), 0, stream>>>(prev_state, prev_belief, stateCat, belBuf1);

    for (int t = 0; t < 32; ++t) {
        short* belPrevBf = (t & 1) ? belBuf0 : belBuf1;
        short* belCurBf  = (t & 1) ? belBuf1 : belBuf0;
        const float* belPrevF = t ? (beliefs + (size_t)(t - 1) * 524288) : prev_belief;
        float* belT = beliefs + (size_t)t * 524288;

        k_embed_state<<<dim3(256), dim3(128), 0, stream>>>(stateCat, sw_es, b_es, hidden);
        k_gru<<<dim3(256), dim3(128), 0, stream>>>(hidden, belPrevBf, belPrevF,
                                                   sw_ih, sw_hh, b_ih, b_hh, belT, belCurBf);
        k_embed_post<<<dim3(256), dim3(128), 0, stream>>>(belCurBf, obs + (size_t)t * 524288,
                                                          sw_ebpo, b_ebpo, hpBuf);
        k_embed_prior<<<dim3(256), dim3(128), 0, stream>>>(belCurBf, poses + (size_t)t * 3072,
                                                           sw_ebpr, w_ebpr, b_ebpr, hqBuf);
        k_head<<<dim3(128), dim3(128), 0, stream>>>(hpBuf, hqBuf, sw_spo, sw_spr, b_spo, b_spr,
                                                    post_noise + (size_t)t * 131072,
                                                    prior_noise + (size_t)t * 131072,
                                                    postMeans + (size_t)t * 131072,
                                                    postStds + (size_t)t * 131072,
                                                    postStates + (size_t)t * 131072,
                                                    priMeans + (size_t)t * 131072,
                                                    priStds + (size_t)t * 131072,
                                                    priStates + (size_t)t * 131072,
                                                    stateCat);
    }
}

// Round 3
// 2894.754 us; speedup vs baseline: 6.9789x; 1.3024x over previous
//
#include <hip/hip_runtime.h>
#include <math.h>

// ---------------------------------------------------------------------------
// RSSM, Round 3: bf16 MFMA, 16x16 wave tiles, 2048-wave GEMMs (8 waves/CU),
// post+prior fused into one launch (4 launches/step), obs pre-converted bf16.
// ---------------------------------------------------------------------------

typedef __attribute__((ext_vector_type(8))) short bf16x8;
typedef __attribute__((ext_vector_type(4))) float f32x4;

#define MFMA(a, b, c) __builtin_amdgcn_mfma_f32_16x16x32_bf16(a, b, c, 0, 0, 0)

__device__ __forceinline__ short f2bf(float f) {
    unsigned u = __float_as_uint(f);
    u += 0x7FFF + ((u >> 16) & 1);   // RNE
    return (short)(u >> 16);
}
__device__ __forceinline__ float sigmoidf_(float x) { return 1.f / (1.f + expf(-x)); }
__device__ __forceinline__ float softplusf_(float x) {
    return fmaxf(x, 0.f) + log1pf(expf(-fabsf(x)));
}
__device__ __forceinline__ f32x4 zero4() { f32x4 v = {0.f, 0.f, 0.f, 0.f}; return v; }

// B-frag pre-swizzle (one wave per 16n x 32k tile):
// out[((nt*KT+kt)*64 + lane)*8 + j] = bf16(W[(kt*32+(lane>>4)*8+j)*N + nt*16 + (lane&15)])
__global__ __launch_bounds__(256) void k_swizzle(const float* __restrict__ W,
                                                 short* __restrict__ out,
                                                 int KT, int N)
{
    int gw = blockIdx.x * 4 + (threadIdx.x >> 6);
    int lane = threadIdx.x & 63;
    int nt = gw / KT, kt = gw % KT;
    const float* src = W + (size_t)(kt * 32 + (lane >> 4) * 8) * N + nt * 16 + (lane & 15);
    short tmp[8];
#pragma unroll
    for (int j = 0; j < 8; ++j) tmp[j] = f2bf(src[(size_t)j * N]);
    *(bf16x8*)(out + (((size_t)gw * 64 + lane) << 3)) = *(const bf16x8*)tmp;
}

// obs fp32 [32*512*1024] -> bf16
__global__ __launch_bounds__(256) void k_obs2bf(const float* __restrict__ obs,
                                                short* __restrict__ out)
{
    size_t i = ((size_t)blockIdx.x * 256 + threadIdx.x) * 8;
    short tmp[8];
#pragma unroll
    for (int j = 0; j < 8; ++j) tmp[j] = f2bf(obs[i + j]);
    *(bf16x8*)(out + i) = *(const bf16x8*)tmp;
}

// init stateCat[512][512] = [prev|prev] bf16, belief buf bf16
__global__ __launch_bounds__(256) void k_init(const float* __restrict__ prev_state,
                                              const float* __restrict__ prev_belief,
                                              short* __restrict__ stateCat,
                                              short* __restrict__ belief1)
{
    int i = blockIdx.x * 256 + threadIdx.x;
    if (i < 262144) {
        int m = i >> 9, c = i & 511;
        stateCat[i] = f2bf(prev_state[m * 256 + (c & 255)]);
    } else {
        int j = i - 262144;
        belief1[j] = f2bf(prev_belief[j]);
    }
}

__device__ __forceinline__ bf16x8 loadA16(const short* A, int m0, int kelem, int strideElems, int lane) {
    return *(const bf16x8*)(A + (size_t)(m0 + (lane & 15)) * strideElems + kelem + ((lane >> 4) << 3));
}
__device__ __forceinline__ bf16x8 loadB16(const short* Bsw, size_t tileIdx, int lane) {
    return *(const bf16x8*)(Bsw + ((tileIdx * 64 + lane) << 3));
}

// ---------------------------------------------------------------------------
// embed_state: hidden = relu(stateCat @ w_es + b).  M=512,K=512,N=1024.
// 2048 waves: mt(32 of 16 rows) x nt(64 of 16 cols); block = 4 waves same mt.
// ---------------------------------------------------------------------------
__global__ __launch_bounds__(256) void k_embed_state(
    const short* __restrict__ A, const short* __restrict__ Bsw,
    const float* __restrict__ bias, short* __restrict__ outBf)
{
    int gw = blockIdx.x * 4 + (threadIdx.x >> 6);
    int lane = threadIdx.x & 63;
    int mt = gw >> 6, nt = gw & 63;
    int m0 = mt * 16;
    f32x4 acc = zero4();
#pragma unroll 4
    for (int kt = 0; kt < 16; ++kt) {
        bf16x8 a = loadA16(A, m0, kt * 32, 512, lane);
        bf16x8 b = loadB16(Bsw, (size_t)nt * 16 + kt, lane);
        acc = MFMA(a, b, acc);
    }
    int q = lane >> 4, cl = lane & 15;
#pragma unroll
    for (int i = 0; i < 4; ++i) {
        int m = m0 + q * 4 + i;
        int n = nt * 16 + cl;
        outBf[(size_t)m * 1024 + n] = f2bf(fmaxf(acc[i] + bias[n], 0.f));
    }
}

// ---------------------------------------------------------------------------
// GRU: 2048 waves: mt(32) x nt(64 of 16 belief cols). r/z over K=2048.
// sw_ih/sw_hh: N=3072 -> 192 ntile16, KT=32; gate g tile base = g*64 + nt.
// ---------------------------------------------------------------------------
__global__ __launch_bounds__(256) void k_gru(
    const short* __restrict__ Hbf, const short* __restrict__ Pbf,
    const float* __restrict__ Pf32,
    const short* __restrict__ sw_ih, const short* __restrict__ sw_hh,
    const float* __restrict__ b_ih, const float* __restrict__ b_hh,
    float* __restrict__ belF32, short* __restrict__ belBf)
{
    int gw = blockIdx.x * 4 + (threadIdx.x >> 6);
    int lane = threadIdx.x & 63;
    int mt = gw >> 6, nt = gw & 63;
    int m0 = mt * 16;
    f32x4 r = zero4(), z = zero4(), ni = zero4(), nh = zero4();

#pragma unroll 4
    for (int kt = 0; kt < 32; ++kt) {   // phase 0: hidden @ w_ih
        bf16x8 a = loadA16(Hbf, m0, kt * 32, 1024, lane);
        bf16x8 br = loadB16(sw_ih, (size_t)(0 * 64 + nt) * 32 + kt, lane);
        bf16x8 bz = loadB16(sw_ih, (size_t)(1 * 64 + nt) * 32 + kt, lane);
        bf16x8 bn = loadB16(sw_ih, (size_t)(2 * 64 + nt) * 32 + kt, lane);
        r = MFMA(a, br, r);
        z = MFMA(a, bz, z);
        ni = MFMA(a, bn, ni);
    }
#pragma unroll 4
    for (int kt = 0; kt < 32; ++kt) {   // phase 1: beliefPrev @ w_hh
        bf16x8 a = loadA16(Pbf, m0, kt * 32, 1024, lane);
        bf16x8 br = loadB16(sw_hh, (size_t)(0 * 64 + nt) * 32 + kt, lane);
        bf16x8 bz = loadB16(sw_hh, (size_t)(1 * 64 + nt) * 32 + kt, lane);
        bf16x8 bn = loadB16(sw_hh, (size_t)(2 * 64 + nt) * 32 + kt, lane);
        r = MFMA(a, br, r);
        z = MFMA(a, bz, z);
        nh = MFMA(a, bn, nh);
    }

    int q = lane >> 4, cl = lane & 15;
#pragma unroll
    for (int i = 0; i < 4; ++i) {
        int m = m0 + q * 4 + i;
        int n = nt * 16 + cl;
        float rr = sigmoidf_(r[i] + b_ih[n] + b_hh[n]);
        float zz = sigmoidf_(z[i] + b_ih[1024 + n] + b_hh[1024 + n]);
        float ng = tanhf(ni[i] + b_ih[2048 + n] + rr * (nh[i] + b_hh[2048 + n]));
        float h = Pf32[(size_t)m * 1024 + n];
        float v = (1.f - zz) * ng + zz * h;
        belF32[(size_t)m * 1024 + n] = v;
        belBf[(size_t)m * 1024 + n] = f2bf(v);
    }
}

// ---------------------------------------------------------------------------
// fused posterior+prior embeds.  gws 0..2047: hp (K=2048: belief|obsBf);
// gws 2048..4095: hq (K=1024 + rank-6 pose epilogue).
// ---------------------------------------------------------------------------
__global__ __launch_bounds__(256) void k_pp(
    const short* __restrict__ Bel, const short* __restrict__ ObsBf,
    const float* __restrict__ Pose,
    const short* __restrict__ sw_ebpo, const short* __restrict__ sw_ebpr,
    const float* __restrict__ Wf_ebpr,
    const float* __restrict__ b_ebpo, const float* __restrict__ b_ebpr,
    short* __restrict__ hpBf, short* __restrict__ hqBf)
{
    int gw = blockIdx.x * 4 + (threadIdx.x >> 6);
    int lane = threadIdx.x & 63;
    int q = lane >> 4, cl = lane & 15;
    if (gw < 2048) {
        int mt = gw >> 6, nt = gw & 63;
        int m0 = mt * 16;
        f32x4 acc = zero4();
#pragma unroll 4
        for (int kt = 0; kt < 32; ++kt) {
            bf16x8 a = loadA16(Bel, m0, kt * 32, 1024, lane);
            bf16x8 b = loadB16(sw_ebpo, (size_t)nt * 64 + kt, lane);
            acc = MFMA(a, b, acc);
        }
#pragma unroll 4
        for (int kt = 32; kt < 64; ++kt) {
            bf16x8 a = loadA16(ObsBf, m0, (kt - 32) * 32, 1024, lane);
            bf16x8 b = loadB16(sw_ebpo, (size_t)nt * 64 + kt, lane);
            acc = MFMA(a, b, acc);
        }
#pragma unroll
        for (int i = 0; i < 4; ++i) {
            int m = m0 + q * 4 + i;
            int n = nt * 16 + cl;
            hpBf[(size_t)m * 1024 + n] = f2bf(fmaxf(acc[i] + b_ebpo[n], 0.f));
        }
    } else {
        int g2 = gw - 2048;
        int mt = g2 >> 6, nt = g2 & 63;
        int m0 = mt * 16;
        f32x4 acc = zero4();
#pragma unroll 4
        for (int kt = 0; kt < 32; ++kt) {
            bf16x8 a = loadA16(Bel, m0, kt * 32, 1024, lane);
            bf16x8 b = loadB16(sw_ebpr, (size_t)nt * 32 + kt, lane);
            acc = MFMA(a, b, acc);
        }
#pragma unroll
        for (int i = 0; i < 4; ++i) {
            int m = m0 + q * 4 + i;
            int n = nt * 16 + cl;
            float v = acc[i] + b_ebpr[n];
#pragma unroll
            for (int p = 0; p < 6; ++p)
                v += Pose[(size_t)m * 6 + p] * Wf_ebpr[(size_t)(1024 + p) * 1024 + n];
            hqBf[(size_t)m * 1024 + n] = f2bf(fmaxf(v, 0.f));
        }
    }
}

// ---------------------------------------------------------------------------
// head: 1024 waves: br(2) x mt(32) x ct(16 of 16 cols); mean+std paired.
// ---------------------------------------------------------------------------
__global__ __launch_bounds__(256) void k_head(
    const short* __restrict__ Hp, const short* __restrict__ Hq,
    const short* __restrict__ sw_spo, const short* __restrict__ sw_spr,
    const float* __restrict__ b_spo, const float* __restrict__ b_spr,
    const float* __restrict__ nPost, const float* __restrict__ nPri,
    float* __restrict__ pM, float* __restrict__ pS, float* __restrict__ pSt,
    float* __restrict__ qM, float* __restrict__ qS, float* __restrict__ qSt,
    short* __restrict__ stateCat)
{
    int gw = blockIdx.x * 4 + (threadIdx.x >> 6);
    int lane = threadIdx.x & 63;
    int br = gw >> 9, rem = gw & 511;
    int mt = rem >> 4, ct = rem & 15;
    int m0 = mt * 16;
    const short* A = br ? Hq : Hp;
    const short* Bsw = br ? sw_spr : sw_spo;
    const float* bias = br ? b_spr : b_spo;
    const float* noise = br ? nPri : nPost;
    float* mO = br ? qM : pM;
    float* sO = br ? qS : pS;
    float* stO = br ? qSt : pSt;
    int catOff = br ? 256 : 0;
    f32x4 ma = zero4(), sa = zero4();
#pragma unroll 4
    for (int kt = 0; kt < 32; ++kt) {
        bf16x8 a = loadA16(A, m0, kt * 32, 1024, lane);
        bf16x8 bm = loadB16(Bsw, (size_t)ct * 32 + kt, lane);
        bf16x8 bs = loadB16(Bsw, (size_t)(16 + ct) * 32 + kt, lane);
        ma = MFMA(a, bm, ma);
        sa = MFMA(a, bs, sa);
    }
    int q = lane >> 4, cl = lane & 15;
#pragma unroll
    for (int i = 0; i < 4; ++i) {
        int m = m0 + q * 4 + i;
        int c = ct * 16 + cl;
        float mean = ma[i] + bias[c];
        float sd = softplusf_(sa[i] + bias[c + 256]) + 0.1f;
        float st = mean + sd * noise[(size_t)m * 256 + c];
        mO[(size_t)m * 256 + c] = mean;
        sO[(size_t)m * 256 + c] = sd;
        stO[(size_t)m * 256 + c] = st;
        stateCat[(size_t)m * 512 + catOff + c] = f2bf(st);
    }
}

// ---------------------------------------------------------------------------
extern "C" void kernel_launch(void* const* d_in, const int* in_sizes, int n_in,
                              void* d_out, int out_size, void* d_ws, size_t ws_size,
                              hipStream_t stream)
{
    const float* prev_state  = (const float*)d_in[0];
    const float* prev_belief = (const float*)d_in[1];
    const float* poses       = (const float*)d_in[2];
    const float* obs         = (const float*)d_in[3];
    const float* post_noise  = (const float*)d_in[4];
    const float* prior_noise = (const float*)d_in[5];
    const float* w_es   = (const float*)d_in[6];
    const float* b_es   = (const float*)d_in[7];
    const float* w_ih   = (const float*)d_in[8];
    const float* w_hh   = (const float*)d_in[9];
    const float* b_ih   = (const float*)d_in[10];
    const float* b_hh   = (const float*)d_in[11];
    const float* w_ebpo = (const float*)d_in[12];
    const float* b_ebpo = (const float*)d_in[13];
    const float* w_spo  = (const float*)d_in[14];
    const float* b_spo  = (const float*)d_in[15];
    const float* w_ebpr = (const float*)d_in[16];
    const float* b_ebpr = (const float*)d_in[17];
    const float* w_spr  = (const float*)d_in[18];
    const float* b_spr  = (const float*)d_in[19];

    float* out = (float*)d_out;
    float* beliefs    = out;
    float* priStates  = out + 16777216;
    float* priMeans   = out + 20971520;
    float* priStds    = out + 25165824;
    float* postStates = out + 29360128;
    float* postMeans  = out + 33554432;
    float* postStds   = out + 37748736;

    short* ws = (short*)d_ws;
    size_t o = 0;
    short* sw_es   = ws + o; o += (size_t)512 * 1024;
    short* sw_ih   = ws + o; o += (size_t)1024 * 3072;
    short* sw_hh   = ws + o; o += (size_t)1024 * 3072;
    short* sw_ebpo = ws + o; o += (size_t)2048 * 1024;
    short* sw_ebpr = ws + o; o += (size_t)1024 * 1024;
    short* sw_spo  = ws + o; o += (size_t)1024 * 512;
    short* sw_spr  = ws + o; o += (size_t)1024 * 512;
    short* hidden  = ws + o; o += (size_t)512 * 1024;
    short* belBuf0 = ws + o; o += (size_t)512 * 1024;
    short* belBuf1 = ws + o; o += (size_t)512 * 1024;
    short* hpBuf   = ws + o; o += (size_t)512 * 1024;
    short* hqBuf   = ws + o; o += (size_t)512 * 1024;
    short* stateCat = ws + o; o += (size_t)512 * 512;
    short* obsBf   = ws + o; o += (size_t)32 * 512 * 1024;

    // ---- pre-pass ----
    k_swizzle<<<dim3(256),  dim3(256), 0, stream>>>(w_es,   sw_es,   16, 1024);
    k_swizzle<<<dim3(1536), dim3(256), 0, stream>>>(w_ih,   sw_ih,   32, 3072);
    k_swizzle<<<dim3(1536), dim3(256), 0, stream>>>(w_hh,   sw_hh,   32, 3072);
    k_swizzle<<<dim3(1024), dim3(256), 0, stream>>>(w_ebpo, sw_ebpo, 64, 1024);
    k_swizzle<<<dim3(512),  dim3(256), 0, stream>>>(w_ebpr, sw_ebpr, 32, 1024);
    k_swizzle<<<dim3(256),  dim3(256), 0, stream>>>(w_spo,  sw_spo,  32, 512);
    k_swizzle<<<dim3(256),  dim3(256), 0, stream>>>(w_spr,  sw_spr,  32, 512);
    k_obs2bf<<<dim3(8192), dim3(256), 0, stream>>>(obs, obsBf);
    k_init<<<dim3(3072), dim3(256), 0, stream>>>(prev_state, prev_belief, stateCat, belBuf1);

    for (int t = 0; t < 32; ++t) {
        short* belPrevBf = (t & 1) ? belBuf0 : belBuf1;
        short* belCurBf  = (t & 1) ? belBuf1 : belBuf0;
        const float* belPrevF = t ? (beliefs + (size_t)(t - 1) * 524288) : prev_belief;
        float* belT = beliefs + (size_t)t * 524288;

        k_embed_state<<<dim3(512), dim3(256), 0, stream>>>(stateCat, sw_es, b_es, hidden);
        k_gru<<<dim3(512), dim3(256), 0, stream>>>(hidden, belPrevBf, belPrevF,
                                                   sw_ih, sw_hh, b_ih, b_hh, belT, belCurBf);
        k_pp<<<dim3(1024), dim3(256), 0, stream>>>(belCurBf, obsBf + (size_t)t * 524288,
                                                   poses + (size_t)t * 3072,
                                                   sw_ebpo, sw_ebpr, w_ebpr,
                                                   b_ebpo, b_ebpr, hpBuf, hqBuf);
        k_head<<<dim3(256), dim3(256), 0, stream>>>(hpBuf, hqBuf, sw_spo, sw_spr, b_spo, b_spr,
                                                    post_noise + (size_t)t * 131072,
                                                    prior_noise + (size_t)t * 131072,
                                                    postMeans + (size_t)t * 131072,
                                                    postStds + (size_t)t * 131072,
                                                    postStates + (size_t)t * 131072,
                                                    priMeans + (size_t)t * 131072,
                                                    priStds + (size_t)t * 131072,
                                                    priStates + (size_t)t * 131072,
                                                    stateCat);
    }
}